// Round 1
// baseline (630.177 us; speedup 1.0000x reference)
//
#include <hip/hip_runtime.h>
#include <math.h>

#define TT 512      // tokens
#define DM 512      // d_model
#define FF 1024     // d_expert
#define NE 64       // experts
#define CH_G 32     // token chunk, gate/up kernel
#define CH_D 28     // token chunk, down kernel (LDS budget)
#define XSTRIDE 516   // 512 + 4 pad floats -> spreads LDS banks
#define HSTRIDE 1028  // 1024 + 4 pad floats

__device__ __forceinline__ float dot4(float4 a, float4 b) {
  return a.x * b.x + a.y * b.y + a.z * b.z + a.w * b.w;
}

__global__ void init_k(int* counts, float* probs) {
  int i = threadIdx.x;
  if (i < NE) { counts[i] = 0; probs[i] = 0.0f; }
}

// one wave per token: logits, softmax accumulation for aux, top-2 routing
__global__ void router_k(const float* __restrict__ x, const float* __restrict__ rw,
                         float* __restrict__ probs_sum, int* __restrict__ top_idx,
                         float* __restrict__ top_w, int* __restrict__ counts) {
  const int t = blockIdx.x;
  const int lane = threadIdx.x;  // 0..63, lane == expert id
  __shared__ float4 xs[DM / 4];
  const float4* xrow = (const float4*)(x + (size_t)t * DM);
  xs[lane] = xrow[lane];
  xs[lane + 64] = xrow[lane + 64];
  __syncthreads();

  const float4* wr = (const float4*)(rw + (size_t)lane * DM);
  float acc = 0.0f;
#pragma unroll 8
  for (int i = 0; i < DM / 4; i++) acc += dot4(wr[i], xs[i]);

  // full softmax -> probs accumulation (aux loss)
  float m = acc;
  for (int off = 32; off; off >>= 1) m = fmaxf(m, __shfl_xor(m, off));
  float ex = expf(acc - m);
  float s = ex;
  for (int off = 32; off; off >>= 1) s += __shfl_xor(s, off);
  atomicAdd(&probs_sum[lane], ex / s);

  // top-1 (tie -> lower index)
  float v = acc; int id = lane;
  for (int off = 32; off; off >>= 1) {
    float ov = __shfl_xor(v, off); int oi = __shfl_xor(id, off);
    if (ov > v || (ov == v && oi < id)) { v = ov; id = oi; }
  }
  // top-2
  float v2 = (lane == id) ? -INFINITY : acc; int id2 = lane;
  for (int off = 32; off; off >>= 1) {
    float ov = __shfl_xor(v2, off); int oi = __shfl_xor(id2, off);
    if (ov > v2 || (ov == v2 && oi < id2)) { v2 = ov; id2 = oi; }
  }

  if (lane == 0) {
    float e1 = expf(v2 - v);           // e^{v1-v0}, v0 >= v1
    float inv = 1.0f / (1.0f + e1);
    top_idx[t * 2] = id;  top_idx[t * 2 + 1] = id2;
    top_w[t * 2] = inv;   top_w[t * 2 + 1] = e1 * inv;
    atomicAdd(&counts[id], 1);
    atomicAdd(&counts[id2], 1);
  }
}

// exclusive scan of counts, zero cursors, compute aux loss
__global__ void offsets_k(const int* __restrict__ counts, int* __restrict__ offs,
                          int* __restrict__ cursor, const float* __restrict__ probs_sum,
                          float* __restrict__ aux_out) {
  const int lane = threadIdx.x;  // 0..63
  __shared__ int cs[NE];
  cs[lane] = counts[lane];
  __syncthreads();
  int off = 0;
  for (int i = 0; i < lane; i++) off += cs[i];
  offs[lane] = off;
  cursor[lane] = 0;

  // aux: v = (probs_sum/T) * E ; var unbiased over 64 experts
  float v = probs_sum[lane] * ((float)NE / (float)TT);
  float s = v;
  for (int o = 32; o; o >>= 1) s += __shfl_xor(s, o);
  float mean = s * (1.0f / NE);
  float d = v - mean;
  float q = d * d;
  for (int o = 32; o; o >>= 1) q += __shfl_xor(q, o);
  if (lane == 0) aux_out[0] = q * (1.0f / (NE - 1));
}

__global__ void scatter_k(const int* __restrict__ top_idx, const float* __restrict__ top_w,
                          const int* __restrict__ offs, int* __restrict__ cursor,
                          int* __restrict__ tok, float* __restrict__ wslot) {
  const int t = threadIdx.x;  // 0..511
#pragma unroll
  for (int k = 0; k < 2; k++) {
    int e = top_idx[t * 2 + k];
    int i = atomicAdd(&cursor[e], 1);
    int sidx = offs[e] + i;
    tok[sidx] = t;
    wslot[sidx] = top_w[t * 2 + k];
  }
}

// grouped gate/up: grid (F/128, NE), 512 threads (8 waves, 16 f-rows each)
__global__ __launch_bounds__(512) void gateup_k(
    const float* __restrict__ x, const float* __restrict__ wg, const float* __restrict__ wu,
    const int* __restrict__ counts, const int* __restrict__ offs,
    const int* __restrict__ tok, float* __restrict__ h) {
  const int e = blockIdx.y;
  const int n = counts[e];
  if (n == 0) return;
  const int f0 = blockIdx.x * 128;
  const int base = offs[e];
  __shared__ float xs[CH_G * XSTRIDE];  // ~66 KB

  const int tid = threadIdx.x;
  const int wave = tid >> 6;
  const int lane = tid & 63;
  const int q = lane & 15;   // D-slice (16 slices x 32 floats)
  const int c = lane >> 4;   // token-in-group 0..3

  for (int c0 = 0; c0 < n; c0 += CH_G) {
    const int nc = min(CH_G, n - c0);
    {  // stage token rows, 16 threads per row
      const int r = tid >> 4, p = tid & 15;
      if (r < nc) {
        const int tk = tok[base + c0 + r];
        const float4* src = (const float4*)(x + (size_t)tk * DM);
        float4* dst = (float4*)(xs + r * XSTRIDE);
#pragma unroll
        for (int k = 0; k < 8; k++) dst[p + 16 * k] = src[p + 16 * k];
      }
    }
    __syncthreads();

    const size_t wbase = ((size_t)e * FF + f0 + wave * 16) * DM + (size_t)q * 32;
    const float4* wg4 = (const float4*)(wg + wbase);  // row step = 128 float4
    const float4* wu4 = (const float4*)(wu + wbase);

    float4 a0[8], b0[8], a1[8], b1[8];
#pragma unroll
    for (int i = 0; i < 8; i++) { a0[i] = wg4[i]; b0[i] = wu4[i]; }

    auto compute = [&](const float4* A, const float4* B, int fi) {
      const int f = f0 + wave * 16 + fi;
      for (int cg = 0; cg < nc; cg += 4) {
        const int cc = cg + c;
        const float4* xv = (const float4*)(xs + cc * XSTRIDE) + q * 8;
        float g = 0.0f, u = 0.0f;
#pragma unroll
        for (int i = 0; i < 8; i++) {
          float4 xx = xv[i];
          g += dot4(A[i], xx);
          u += dot4(B[i], xx);
        }
        g += __shfl_xor(g, 1); u += __shfl_xor(u, 1);
        g += __shfl_xor(g, 2); u += __shfl_xor(u, 2);
        g += __shfl_xor(g, 4); u += __shfl_xor(u, 4);
        g += __shfl_xor(g, 8); u += __shfl_xor(u, 8);
        if (q == 0 && cc < nc) {
          float sg = g / (1.0f + expf(-g));  // silu
          h[(size_t)(base + c0 + cc) * FF + f] = sg * u;
        }
      }
    };

    for (int fi = 0; fi < 16; fi += 2) {
#pragma unroll
      for (int i = 0; i < 8; i++) {  // prefetch row fi+1
        a1[i] = wg4[(size_t)(fi + 1) * 128 + i];
        b1[i] = wu4[(size_t)(fi + 1) * 128 + i];
      }
      compute(a0, b0, fi);
      if (fi + 2 < 16) {
#pragma unroll
        for (int i = 0; i < 8; i++) {  // prefetch row fi+2
          a0[i] = wg4[(size_t)(fi + 2) * 128 + i];
          b0[i] = wu4[(size_t)(fi + 2) * 128 + i];
        }
      }
      compute(a1, b1, fi + 1);
    }
    __syncthreads();
  }
}

// grouped down-proj + weighted scatter-add: grid (D/128, NE), 512 threads
__global__ __launch_bounds__(512) void down_k(
    const float* __restrict__ h, const float* __restrict__ wd,
    const int* __restrict__ counts, const int* __restrict__ offs,
    const int* __restrict__ tok, const float* __restrict__ wslot,
    float* __restrict__ out) {
  const int e = blockIdx.y;
  const int n = counts[e];
  if (n == 0) return;
  const int d0 = blockIdx.x * 128;
  const int base = offs[e];
  __shared__ float hs[CH_D * HSTRIDE];  // ~115 KB
  __shared__ int ts[CH_D];
  __shared__ float tws[CH_D];

  const int tid = threadIdx.x;
  const int wave = tid >> 6;
  const int lane = tid & 63;
  const int q = lane & 15;   // F-slice (16 slices x 64 floats)
  const int c = lane >> 4;   // token-in-group 0..3

  for (int c0 = 0; c0 < n; c0 += CH_D) {
    const int nc = min(CH_D, n - c0);
    {  // stage h rows, 16 threads per row
      const int r = tid >> 4, p = tid & 15;
      if (r < nc) {
        if (p == 0) { ts[r] = tok[base + c0 + r]; tws[r] = wslot[base + c0 + r]; }
        const float4* src = (const float4*)(h + (size_t)(base + c0 + r) * FF);
        float4* dst = (float4*)(hs + r * HSTRIDE);
#pragma unroll
        for (int k = 0; k < 16; k++) dst[p + 16 * k] = src[p + 16 * k];
      }
    }
    __syncthreads();

    const size_t wbase = ((size_t)e * DM + d0 + wave * 16) * FF + (size_t)q * 64;
    const float4* wd4 = (const float4*)(wd + wbase);  // row step = 256 float4

    float4 a0[16], a1[16];
#pragma unroll
    for (int i = 0; i < 16; i++) a0[i] = wd4[i];

    auto compute = [&](const float4* A, int fi) {
      const int d = d0 + wave * 16 + fi;
      for (int cg = 0; cg < nc; cg += 4) {
        const int cc = cg + c;
        const float4* hv = (const float4*)(hs + cc * HSTRIDE) + q * 16;
        float s = 0.0f;
#pragma unroll
        for (int i = 0; i < 16; i++) s += dot4(A[i], hv[i]);
        s += __shfl_xor(s, 1);
        s += __shfl_xor(s, 2);
        s += __shfl_xor(s, 4);
        s += __shfl_xor(s, 8);
        if (q == 0 && cc < nc) {
          atomicAdd(&out[(size_t)ts[cc] * DM + d], s * tws[cc]);
        }
      }
    };

    for (int fi = 0; fi < 16; fi += 2) {
#pragma unroll
      for (int i = 0; i < 16; i++) a1[i] = wd4[(size_t)(fi + 1) * 256 + i];
      compute(a0, fi);
      if (fi + 2 < 16) {
#pragma unroll
        for (int i = 0; i < 16; i++) a0[i] = wd4[(size_t)(fi + 2) * 256 + i];
      }
      compute(a1, fi + 1);
    }
    __syncthreads();
  }
}

extern "C" void kernel_launch(void* const* d_in, const int* in_sizes, int n_in,
                              void* d_out, int out_size, void* d_ws, size_t ws_size,
                              hipStream_t stream) {
  const float* x  = (const float*)d_in[0];
  const float* rw = (const float*)d_in[1];
  const float* wg = (const float*)d_in[2];
  const float* wu = (const float*)d_in[3];
  const float* wd = (const float*)d_in[4];
  float* out = (float*)d_out;

  char* ws = (char*)d_ws;
  float* h = (float*)ws;                                   // 1024*1024 f = 4 MB
  size_t off = (size_t)(TT * 2) * FF * sizeof(float);
  int* counts  = (int*)(ws + off); off += NE * sizeof(int);
  int* cursor  = (int*)(ws + off); off += NE * sizeof(int);
  int* offs    = (int*)(ws + off); off += NE * sizeof(int);
  int* top_idx = (int*)(ws + off); off += (size_t)TT * 2 * sizeof(int);
  int* tok     = (int*)(ws + off); off += (size_t)TT * 2 * sizeof(int);
  float* probs = (float*)(ws + off); off += NE * sizeof(float);
  float* top_w = (float*)(ws + off); off += (size_t)TT * 2 * sizeof(float);
  float* wslot = (float*)(ws + off); off += (size_t)TT * 2 * sizeof(float);

  hipMemsetAsync(d_out, 0, (size_t)out_size * sizeof(float), stream);
  init_k<<<1, 64, 0, stream>>>(counts, probs);
  router_k<<<TT, 64, 0, stream>>>(x, rw, probs, top_idx, top_w, counts);
  offsets_k<<<1, 64, 0, stream>>>(counts, offs, cursor, probs, out + (size_t)TT * DM);
  scatter_k<<<1, TT, 0, stream>>>(top_idx, top_w, offs, cursor, tok, wslot);
  gateup_k<<<dim3(FF / 128, NE), 512, 0, stream>>>(x, wg, wu, counts, offs, tok, h);
  down_k<<<dim3(DM / 128, NE), 512, 0, stream>>>(h, wd, counts, offs, tok, wslot, out);
}

// Round 2
// 501.929 us; speedup vs baseline: 1.2555x; 1.2555x over previous
//
#include <hip/hip_runtime.h>
#include <math.h>

#define TT 512      // tokens
#define DM 512      // d_model
#define FF 1024     // d_expert
#define NE 64       // experts
#define CH 32       // token chunk (both big kernels)
#define ST 516      // 512 + 4 pad floats

__device__ __forceinline__ float dot4(float4 a, float4 b) {
  return a.x * b.x + a.y * b.y + a.z * b.z + a.w * b.w;
}

__global__ void init_k(int* counts, float* probs) {
  int i = threadIdx.x;
  if (i < NE) { counts[i] = 0; probs[i] = 0.0f; }
}

// one wave per token: logits, softmax accumulation for aux, top-2 routing
__global__ void router_k(const float* __restrict__ x, const float* __restrict__ rw,
                         float* __restrict__ probs_sum, int* __restrict__ top_idx,
                         float* __restrict__ top_w, int* __restrict__ counts) {
  const int t = blockIdx.x;
  const int lane = threadIdx.x;  // 0..63, lane == expert id
  __shared__ float4 xs[DM / 4];
  const float4* xrow = (const float4*)(x + (size_t)t * DM);
  xs[lane] = xrow[lane];
  xs[lane + 64] = xrow[lane + 64];
  __syncthreads();

  const float4* wr = (const float4*)(rw + (size_t)lane * DM);
  float acc = 0.0f;
#pragma unroll 8
  for (int i = 0; i < DM / 4; i++) acc += dot4(wr[i], xs[i]);

  // full softmax -> probs accumulation (aux loss)
  float m = acc;
  for (int off = 32; off; off >>= 1) m = fmaxf(m, __shfl_xor(m, off));
  float ex = expf(acc - m);
  float s = ex;
  for (int off = 32; off; off >>= 1) s += __shfl_xor(s, off);
  atomicAdd(&probs_sum[lane], ex / s);

  // top-1 (tie -> lower index)
  float v = acc; int id = lane;
  for (int off = 32; off; off >>= 1) {
    float ov = __shfl_xor(v, off); int oi = __shfl_xor(id, off);
    if (ov > v || (ov == v && oi < id)) { v = ov; id = oi; }
  }
  // top-2
  float v2 = (lane == id) ? -INFINITY : acc; int id2 = lane;
  for (int off = 32; off; off >>= 1) {
    float ov = __shfl_xor(v2, off); int oi = __shfl_xor(id2, off);
    if (ov > v2 || (ov == v2 && oi < id2)) { v2 = ov; id2 = oi; }
  }

  if (lane == 0) {
    float e1 = expf(v2 - v);           // e^{v1-v0}, v0 >= v1
    float inv = 1.0f / (1.0f + e1);
    top_idx[t * 2] = id;  top_idx[t * 2 + 1] = id2;
    top_w[t * 2] = inv;   top_w[t * 2 + 1] = e1 * inv;
    atomicAdd(&counts[id], 1);
    atomicAdd(&counts[id2], 1);
  }
}

// exclusive scan of counts, zero cursors, compute aux loss
__global__ void offsets_k(const int* __restrict__ counts, int* __restrict__ offs,
                          int* __restrict__ cursor, const float* __restrict__ probs_sum,
                          float* __restrict__ aux_out) {
  const int lane = threadIdx.x;  // 0..63
  __shared__ int cs[NE];
  cs[lane] = counts[lane];
  __syncthreads();
  int off = 0;
  for (int i = 0; i < lane; i++) off += cs[i];
  offs[lane] = off;
  cursor[lane] = 0;

  // aux: v = (probs_sum/T) * E ; var unbiased over 64 experts
  float v = probs_sum[lane] * ((float)NE / (float)TT);
  float s = v;
  for (int o = 32; o; o >>= 1) s += __shfl_xor(s, o);
  float mean = s * (1.0f / NE);
  float d = v - mean;
  float q = d * d;
  for (int o = 32; o; o >>= 1) q += __shfl_xor(q, o);
  if (lane == 0) aux_out[0] = q * (1.0f / (NE - 1));
}

__global__ void scatter_k(const int* __restrict__ top_idx, const float* __restrict__ top_w,
                          const int* __restrict__ offs, int* __restrict__ cursor,
                          int* __restrict__ tok, float* __restrict__ wslot) {
  const int t = threadIdx.x;  // 0..511
#pragma unroll
  for (int k = 0; k < 2; k++) {
    int e = top_idx[t * 2 + k];
    int i = atomicAdd(&cursor[e], 1);
    int sidx = offs[e] + i;
    tok[sidx] = t;
    wslot[sidx] = top_w[t * 2 + k];
  }
}

// grouped gate/up: grid (FF/128, NE), 512 threads (8 waves, 16 f-rows each)
// lane split: q = lane&31 owns float4s {q+32i}, c = lane>>5 -> token parity
__global__ __launch_bounds__(512, 4) void gateup_k(
    const float* __restrict__ x, const float* __restrict__ wg, const float* __restrict__ wu,
    const int* __restrict__ counts, const int* __restrict__ offs,
    const int* __restrict__ tok, float* __restrict__ h) {
  const int e = blockIdx.y;
  const int n = counts[e];
  if (n == 0) return;
  const int f0 = blockIdx.x * 128;
  const int base = offs[e];
  __shared__ float xs[CH * ST];  // 66 KB

  const int tid = threadIdx.x;
  const int wave = tid >> 6;
  const int lane = tid & 63;
  const int q = lane & 31;
  const int c = lane >> 5;

  for (int c0 = 0; c0 < n; c0 += CH) {
    const int nc = min(CH, n - c0);
    {  // stage token rows, 16 threads per row (interleaved float4s)
      const int r = tid >> 4, p = tid & 15;
      if (r < nc) {
        const int tk = tok[base + c0 + r];
        const float4* src = (const float4*)(x + (size_t)tk * DM);
        float4* dst = (float4*)(xs + r * ST);
#pragma unroll
        for (int k = 0; k < 8; k++) dst[p + 16 * k] = src[p + 16 * k];
      }
    }
    __syncthreads();

    const int fbase = f0 + wave * 16;
    const float4* gw = (const float4*)wg + (size_t)(e * FF + fbase) * 128 + q;
    const float4* uw = (const float4*)wu + (size_t)(e * FF + fbase) * 128 + q;

    float4 a0[4], b0[4], a1[4], b1[4];
#pragma unroll
    for (int i = 0; i < 4; i++) { a0[i] = gw[32 * i]; b0[i] = uw[32 * i]; }

    auto compute = [&](const float4* A, const float4* B, int fi) {
      const int f = fbase + fi;
      for (int cg = 0; cg < nc; cg += 2) {
        const int cc = cg + c;
        const float4* xv = (const float4*)(xs + cc * ST) + q;
        float g = 0.0f, u = 0.0f;
#pragma unroll
        for (int i = 0; i < 4; i++) {
          float4 xx = xv[32 * i];
          g += dot4(A[i], xx);
          u += dot4(B[i], xx);
        }
        g += __shfl_xor(g, 1);  u += __shfl_xor(u, 1);
        g += __shfl_xor(g, 2);  u += __shfl_xor(u, 2);
        g += __shfl_xor(g, 4);  u += __shfl_xor(u, 4);
        g += __shfl_xor(g, 8);  u += __shfl_xor(u, 8);
        g += __shfl_xor(g, 16); u += __shfl_xor(u, 16);
        if (q == 0 && cc < nc) {
          float sg = g / (1.0f + expf(-g));  // silu
          h[(size_t)(base + c0 + cc) * FF + f] = sg * u;
        }
      }
    };

    for (int fi = 0; fi < 16; fi += 2) {
#pragma unroll
      for (int i = 0; i < 4; i++) {  // prefetch row fi+1
        a1[i] = gw[(fi + 1) * 128 + 32 * i];
        b1[i] = uw[(fi + 1) * 128 + 32 * i];
      }
      compute(a0, b0, fi);
      if (fi + 2 < 16) {
#pragma unroll
        for (int i = 0; i < 4; i++) {  // prefetch row fi+2
          a0[i] = gw[(fi + 2) * 128 + 32 * i];
          b0[i] = uw[(fi + 2) * 128 + 32 * i];
        }
      }
      compute(a1, b1, fi + 1);
    }
    __syncthreads();
  }
}

// grouped down-proj + weighted scatter-add: grid (DM/128, NE, 2 F-halves)
// each wave owns 16 d-rows, processed as pairs (sA,sB share the h fragment)
__global__ __launch_bounds__(512, 4) void down_k(
    const float* __restrict__ h, const float* __restrict__ wd,
    const int* __restrict__ counts, const int* __restrict__ offs,
    const int* __restrict__ tok, const float* __restrict__ wslot,
    float* __restrict__ out) {
  const int e = blockIdx.y;
  const int n = counts[e];
  if (n == 0) return;
  const int d0 = blockIdx.x * 128;
  const int fh = blockIdx.z;          // F half: cols fh*512 .. fh*512+511
  const int base = offs[e];
  __shared__ float hs[CH * ST];  // 66 KB
  __shared__ int ts[CH];
  __shared__ float tws[CH];

  const int tid = threadIdx.x;
  const int wave = tid >> 6;
  const int lane = tid & 63;
  const int q = lane & 31;
  const int c = lane >> 5;

  for (int c0 = 0; c0 < n; c0 += CH) {
    const int nc = min(CH, n - c0);
    {  // stage h half-rows, 16 threads per row (interleaved float4s)
      const int r = tid >> 4, p = tid & 15;
      if (r < nc) {
        if (p == 0) { ts[r] = tok[base + c0 + r]; tws[r] = wslot[base + c0 + r]; }
        const float4* src = (const float4*)(h + (size_t)(base + c0 + r) * FF + fh * 512);
        float4* dst = (float4*)(hs + r * ST);
#pragma unroll
        for (int k = 0; k < 8; k++) dst[p + 16 * k] = src[p + 16 * k];
      }
    }
    __syncthreads();

    const int dbase = d0 + wave * 16;
    const float4* wr = (const float4*)wd + (size_t)(e * DM + dbase) * 256 + fh * 128 + q;
    // row step = 256 float4

    float4 A0[4], B0[4], A1[4], B1[4];
#pragma unroll
    for (int i = 0; i < 4; i++) { A0[i] = wr[32 * i]; B0[i] = wr[256 + 32 * i]; }

    auto compute = [&](const float4* A, const float4* B, int dj) {
      const int dd = dbase + dj;
      for (int cg = 0; cg < nc; cg += 2) {
        const int cc = cg + c;
        const float4* hv = (const float4*)(hs + cc * ST) + q;
        float sA = 0.0f, sB = 0.0f;
#pragma unroll
        for (int i = 0; i < 4; i++) {
          float4 hh = hv[32 * i];
          sA += dot4(A[i], hh);
          sB += dot4(B[i], hh);
        }
        sA += __shfl_xor(sA, 1);  sB += __shfl_xor(sB, 1);
        sA += __shfl_xor(sA, 2);  sB += __shfl_xor(sB, 2);
        sA += __shfl_xor(sA, 4);  sB += __shfl_xor(sB, 4);
        sA += __shfl_xor(sA, 8);  sB += __shfl_xor(sB, 8);
        sA += __shfl_xor(sA, 16); sB += __shfl_xor(sB, 16);
        if (q == 0 && cc < nc) {
          const float w = tws[cc];
          float* op = out + (size_t)ts[cc] * DM + dd;
          atomicAdd(op, sA * w);
          atomicAdd(op + 1, sB * w);
        }
      }
    };

    for (int dj = 0; dj < 16; dj += 4) {
#pragma unroll
      for (int i = 0; i < 4; i++) {  // prefetch rows dj+2, dj+3
        A1[i] = wr[(dj + 2) * 256 + 32 * i];
        B1[i] = wr[(dj + 3) * 256 + 32 * i];
      }
      compute(A0, B0, dj);
      if (dj + 4 < 16) {
#pragma unroll
        for (int i = 0; i < 4; i++) {  // prefetch rows dj+4, dj+5
          A0[i] = wr[(dj + 4) * 256 + 32 * i];
          B0[i] = wr[(dj + 5) * 256 + 32 * i];
        }
      }
      compute(A1, B1, dj + 2);
    }
    __syncthreads();
  }
}

extern "C" void kernel_launch(void* const* d_in, const int* in_sizes, int n_in,
                              void* d_out, int out_size, void* d_ws, size_t ws_size,
                              hipStream_t stream) {
  const float* x  = (const float*)d_in[0];
  const float* rw = (const float*)d_in[1];
  const float* wg = (const float*)d_in[2];
  const float* wu = (const float*)d_in[3];
  const float* wd = (const float*)d_in[4];
  float* out = (float*)d_out;

  char* ws = (char*)d_ws;
  float* h = (float*)ws;                                   // 1024 slots x 1024 f = 4 MB
  size_t off = (size_t)(TT * 2) * FF * sizeof(float);
  int* counts  = (int*)(ws + off); off += NE * sizeof(int);
  int* cursor  = (int*)(ws + off); off += NE * sizeof(int);
  int* offs    = (int*)(ws + off); off += NE * sizeof(int);
  int* top_idx = (int*)(ws + off); off += (size_t)TT * 2 * sizeof(int);
  int* tok     = (int*)(ws + off); off += (size_t)TT * 2 * sizeof(int);
  float* probs = (float*)(ws + off); off += NE * sizeof(float);
  float* top_w = (float*)(ws + off); off += (size_t)TT * 2 * sizeof(float);
  float* wslot = (float*)(ws + off); off += (size_t)TT * 2 * sizeof(float);

  hipMemsetAsync(d_out, 0, (size_t)out_size * sizeof(float), stream);
  init_k<<<1, 64, 0, stream>>>(counts, probs);
  router_k<<<TT, 64, 0, stream>>>(x, rw, probs, top_idx, top_w, counts);
  offsets_k<<<1, 64, 0, stream>>>(counts, offs, cursor, probs, out + (size_t)TT * DM);
  scatter_k<<<1, TT, 0, stream>>>(top_idx, top_w, offs, cursor, tok, wslot);
  gateup_k<<<dim3(FF / 128, NE), 512, 0, stream>>>(x, wg, wu, counts, offs, tok, h);
  down_k<<<dim3(DM / 128, NE, 2), 512, 0, stream>>>(h, wd, counts, offs, tok, wslot, out);
}